// Round 7
// baseline (11141.404 us; speedup 1.0000x reference)
//
#include <hip/hip_runtime.h>
#include <hip/hip_bf16.h>

#define B_ 256
#define T_ 256
#define I_ 512
#define H_ 1024

typedef _Float16 half8 __attribute__((ext_vector_type(8)));
typedef float floatx4 __attribute__((ext_vector_type(4)));

__device__ __forceinline__ float fsig(float x) { return 1.f / (1.f + __expf(-x)); }
__device__ __forceinline__ float ftanh(float x) { return 1.f - 2.f / (__expf(2.f * x) + 1.f); }

// agent-scope write-through f16 store (visible cross-XCD at L3 without L2 flush)
__device__ __forceinline__ void st_h16(_Float16* p, _Float16 v) {
  unsigned short u = __builtin_bit_cast(unsigned short, v);
  __hip_atomic_store((unsigned short*)p, u, __ATOMIC_RELAXED, __HIP_MEMORY_SCOPE_AGENT);
}

// Permuted gate-row order: n' -> orig row g*H + h, g=(n'&63)>>4, h=(n'>>6)*16+(n'&15).

__global__ __launch_bounds__(256) void prep_w(
    _Float16* __restrict__ dst, const float* __restrict__ src, int K) {
  const int np = blockIdx.y;
  const int k = blockIdx.x * 256 + threadIdx.x;
  const int cc = np & 63, g = cc >> 4, j = cc & 15;
  const int orig = g * H_ + (np >> 6) * 16 + j;
  dst[(size_t)np * K + k] = (_Float16)src[(size_t)orig * K + k];
}

__global__ __launch_bounds__(256) void prep_bias(
    float* __restrict__ bs0, float* __restrict__ bs1,
    const float* __restrict__ bih0, const float* __restrict__ bhh0,
    const float* __restrict__ bih1, const float* __restrict__ bhh1) {
  const int np = blockIdx.x * 256 + threadIdx.x;   // grid 16
  const int cc = np & 63, g = cc >> 4, j = cc & 15;
  const int orig = g * H_ + (np >> 6) * 16 + j;
  bs0[np] = bih0[orig] + bhh0[orig];
  bs1[np] = bih1[orig] + bhh1[orig];
}

struct MegaArgs {
  const float* ctx;
  const _Float16* W0p;  const _Float16* W1p;
  const _Float16* Wh0p; const _Float16* Wh1p;
  const float* bs0; const float* bs1;
  _Float16* h1ring; _Float16* h2ring;     // [2][B_*H_]
  _Float16* xg0ring; _Float16* xg1ring;   // [2][B_*4096] (block-local)
  float* hF;
  const float* init;
  unsigned* flags;                        // [256] progress flags
};

__device__ __forceinline__ void publish(unsigned* flags, int bid, unsigned v) {
  __syncthreads();
  if (threadIdx.x == 0) {
    asm volatile("" ::: "memory");
    __hip_atomic_store(&flags[bid], v, __ATOMIC_RELAXED, __HIP_MEMORY_SCOPE_AGENT);
  }
}

__device__ __forceinline__ void wait_strip(unsigned* flags, int strip, unsigned tgt) {
  if (threadIdx.x < 64) {
    unsigned* f0 = flags + strip * 64 + threadIdx.x;
    unsigned* f1 = flags + 128 + strip * 64 + threadIdx.x;
    for (;;) {
      const unsigned a = __hip_atomic_load(f0, __ATOMIC_RELAXED, __HIP_MEMORY_SCOPE_AGENT);
      const unsigned b = __hip_atomic_load(f1, __ATOMIC_RELAXED, __HIP_MEMORY_SCOPE_AGENT);
      if (__all(a >= tgt && b >= tgt)) break;
      __builtin_amdgcn_s_sleep(1);
    }
    __builtin_amdgcn_fence(__ATOMIC_ACQUIRE, "agent");
  }
  __syncthreads();
}

// K-split input GEMM: wave w owns K-slice [w*gK/4, ...), all 128 rows x 64 cols.
// bf[j2][n] register B-fragments; A direct per-lane loads, 2-deep j2 ring.
template<int NJ, int AMODE>
__device__ __forceinline__ void kgemm(const void* aptr, size_t rstride,
                                      const half8 (&bf)[8][4], floatx4 (&gacc)[8][4]) {
  const float*    af32 = (const float*)aptr;
  const _Float16* af16 = (const _Float16*)aptr;
  half8 ag[2][8];
  auto ldA = [&](int j2, int m) -> half8 {
    if (AMODE == 0) {
      const float* p = af32 + (size_t)m * 16 * rstride + j2 * 32;
      float4 f0 = *(const float4*)(p);
      float4 f1 = *(const float4*)(p + 4);
      half8 h;
      h[0] = (_Float16)f0.x; h[1] = (_Float16)f0.y;
      h[2] = (_Float16)f0.z; h[3] = (_Float16)f0.w;
      h[4] = (_Float16)f1.x; h[5] = (_Float16)f1.y;
      h[6] = (_Float16)f1.z; h[7] = (_Float16)f1.w;
      return h;
    } else {
      return *(const half8*)(af16 + (size_t)m * 16 * rstride + j2 * 32);
    }
  };
  #pragma unroll
  for (int m = 0; m < 8; ++m) ag[0][m] = ldA(0, m);
  #pragma unroll
  for (int m = 0; m < 8; ++m) ag[1][m] = ldA(1, m);
  #pragma unroll
  for (int j2 = 0; j2 < NJ; ++j2) {
    half8 am[8];
    #pragma unroll
    for (int m = 0; m < 8; ++m) am[m] = ag[j2 & 1][m];
    if (j2 + 2 < NJ) {
      #pragma unroll
      for (int m = 0; m < 8; ++m) ag[j2 & 1][m] = ldA(j2 + 2, m);
    }
    #pragma unroll
    for (int m = 0; m < 8; ++m)
      #pragma unroll
      for (int n = 0; n < 4; ++n)
        gacc[m][n] = __builtin_amdgcn_mfma_f32_16x16x32_f16(am[m], bf[j2][n], gacc[m][n], 0, 0, 0);
  }
}

// Persistent fused kernel: 256 blocks (1/CU). bid>>7=layer, (bid>>6)&1=strip, bid&63=colblock.
// Schedule: L0-rec t=s-1 (s:1..256); L0-gemm xg0[t=s] (s:0..255);
//           L1-gemm tau=s-2 (s:2..257); L1-rec t=s-3 (s:3..258). Rings depth 2.
__global__ __launch_bounds__(256, 1) void mega(MegaArgs a) {
  const int bid = blockIdx.x, tid = threadIdx.x;
  const int layer = bid >> 7, strip = (bid >> 6) & 1, nb = bid & 63;
  const int row0 = strip * 128;
  const int w = tid >> 6, lane = tid & 63, l15 = lane & 15, l4 = lane >> 4;
  const int kg = l4 * 8;

  __shared__ _Float16 whb[64 * 1024];   // 128 KB: resident W_hh slice (swizzled)
  __shared__ float red[64 * 65];        // 16.25 KB: gemm K-split reduce buffer

  // ---- init h rings (slot 1 = t=-1 state), write-through ----
  {
    const int idx = (bid * 256 + tid) * 4;
    const float4 v = *(const float4*)(a.init + idx);
    st_h16(a.h1ring + B_ * H_ + idx,     (_Float16)v.x);
    st_h16(a.h1ring + B_ * H_ + idx + 1, (_Float16)v.y);
    st_h16(a.h1ring + B_ * H_ + idx + 2, (_Float16)v.z);
    st_h16(a.h1ring + B_ * H_ + idx + 3, (_Float16)v.w);
    st_h16(a.h2ring + B_ * H_ + idx,     (_Float16)v.x);
    st_h16(a.h2ring + B_ * H_ + idx + 1, (_Float16)v.y);
    st_h16(a.h2ring + B_ * H_ + idx + 2, (_Float16)v.z);
    st_h16(a.h2ring + B_ * H_ + idx + 3, (_Float16)v.w);
  }

  // ---- stage resident W_hh slice -> LDS (swizzled granules) ----
  {
    const _Float16* Whp = (layer ? a.Wh1p : a.Wh0p) + (size_t)nb * 64 * 1024;
    const int row = tid & 63;
    const int gb = (tid >> 6) * 32;
    #pragma unroll
    for (int i = 0; i < 32; ++i) {
      const int g = gb + i;
      half8 v = *(const half8*)(Whp + (size_t)row * 1024 + g * 8);
      *(half8*)(whb + row * 1024 + ((g ^ (row & 7)) * 8)) = v;
    }
  }

  // ---- K-split B-fragments for input GEMM (reg-resident) ----
  const _Float16* Wg = layer ? a.W1p : a.W0p;
  const int gK = layer ? 1024 : 512;
  const int ksb = w * (gK >> 2);
  half8 bf[8][4];
  #pragma unroll
  for (int j2 = 0; j2 < 8; ++j2) {
    if (j2 < (layer ? 8 : 4)) {
      #pragma unroll
      for (int n = 0; n < 4; ++n)
        bf[j2][n] = *(const half8*)(Wg + (size_t)(nb * 64 + n * 16 + l15) * gK + ksb + j2 * 32 + kg);
    }
  }
  const float bvf = (layer ? a.bs1 : a.bs0)[nb * 64 + (tid & 63)];

  float cst[8] = {0.f, 0.f, 0.f, 0.f, 0.f, 0.f, 0.f, 0.f};
  const int hu = nb * 16 + l15;

  publish(a.flags, bid, 1u);

  for (int s = 0; s <= 258; ++s) {
    wait_strip(a.flags, strip, (unsigned)(s + 1));

    // ================= recurrent (h @ W_hh, K=1024, direct-A, LDS-B) =================
    const bool recAct = layer ? (s >= 3 && s <= 258) : (s >= 1 && s <= 256);
    if (recAct) {
      const _Float16* Asrc = (layer ? a.h2ring : a.h1ring) + (size_t)(s & 1) * (B_ * H_);
      const _Float16* xg = (layer ? a.xg1ring : a.xg0ring) + (size_t)((s - 1) & 1) * (B_ * 4096);
      // prefetch xg gate values into regs (consumed at cell update)
      float xgf[8][4];
      #pragma unroll
      for (int m = 0; m < 2; ++m)
        #pragma unroll
        for (int r = 0; r < 4; ++r) {
          const int brow = row0 + w * 32 + m * 16 + l4 * 4 + r;
          const _Float16* xr = xg + (size_t)brow * 4096 + nb * 64;
          #pragma unroll
          for (int g = 0; g < 4; ++g) xgf[m * 4 + r][g] = (float)xr[g * 16 + l15];
        }
      // rec GEMM: wave w rows w*32..+32; per-lane direct A-fragment loads, 8-deep ring
      const _Float16* ar0 = Asrc + (size_t)(row0 + w * 32 + l15) * H_ + kg;
      const _Float16* ar1 = ar0 + (size_t)16 * H_;
      floatx4 racc[2][4] = {};
      half8 arg[8][2];
      #pragma unroll
      for (int j = 0; j < 8; ++j) {
        arg[j][0] = *(const half8*)(ar0 + j * 32);
        arg[j][1] = *(const half8*)(ar1 + j * 32);
      }
      #pragma unroll
      for (int j = 0; j < 32; ++j) {
        half8 a0 = arg[j & 7][0], a1 = arg[j & 7][1];
        if (j + 8 < 32) {
          arg[j & 7][0] = *(const half8*)(ar0 + (j + 8) * 32);
          arg[j & 7][1] = *(const half8*)(ar1 + (j + 8) * 32);
        }
        #pragma unroll
        for (int n = 0; n < 4; ++n) {
          const int wrow = n * 16 + l15;
          half8 wb = *(const half8*)(whb + wrow * 1024 + (((j * 4 + l4) ^ (wrow & 7)) * 8));
          racc[0][n] = __builtin_amdgcn_mfma_f32_16x16x32_f16(a0, wb, racc[0][n], 0, 0, 0);
          racc[1][n] = __builtin_amdgcn_mfma_f32_16x16x32_f16(a1, wb, racc[1][n], 0, 0, 0);
        }
      }
      // ---- register-local cell update ----
      const int t = layer ? (s - 3) : (s - 1);
      _Float16* hw = (layer ? a.h2ring : a.h1ring) + (size_t)((s - 1) & 1) * (B_ * H_);
      #pragma unroll
      for (int m = 0; m < 2; ++m) {
        #pragma unroll
        for (int r = 0; r < 4; ++r) {
          const int brow = row0 + w * 32 + m * 16 + l4 * 4 + r;
          const float gi = racc[m][0][r] + xgf[m * 4 + r][0];
          const float gf = racc[m][1][r] + xgf[m * 4 + r][1];
          const float gg = racc[m][2][r] + xgf[m * 4 + r][2];
          const float go = racc[m][3][r] + xgf[m * 4 + r][3];
          const float si = fsig(gi), sf = fsig(gf), so = fsig(go);
          const float tg = ftanh(gg);
          const float cn = sf * cst[m * 4 + r] + si * tg;
          const float hn = so * ftanh(cn);
          cst[m * 4 + r] = cn;
          st_h16(hw + (size_t)brow * H_ + hu, (_Float16)hn);
          if (layer == 1 && t == 255) a.hF[(size_t)brow * H_ + hu] = hn;
        }
      }
    }

    if (layer == 0) publish(a.flags, bid, (unsigned)(s + 2));  // h1[t=s-1] visible

    // ================= input-GEMM (K-split waves, reg-B, direct-A) =================
    const bool gAct = layer ? (s >= 2 && s <= 257) : (s <= 255);
    if (gAct) {
      _Float16* og = (layer ? a.xg1ring : a.xg0ring) + (size_t)(s & 1) * (B_ * 4096);
      floatx4 gacc[8][4] = {};
      if (layer) {
        const _Float16* ab = a.h1ring + (size_t)(s & 1) * (B_ * H_)
                           + (size_t)(row0 + l15) * H_ + ksb + kg;
        kgemm<8, 1>(ab, H_, bf, gacc);
      } else {
        const float* ab = a.ctx + (size_t)(row0 + l15) * (T_ * I_) + (size_t)s * I_ + ksb + kg;
        kgemm<4, 0>(ab, T_ * I_, bf, gacc);
      }
      // reduce 4 K-partials via LDS (sequential wave adds), finish + store
      #pragma unroll
      for (int p = 0; p < 2; ++p) {
        __syncthreads();
        if (w == 0) {
          #pragma unroll
          for (int mi = 0; mi < 4; ++mi)
            #pragma unroll
            for (int n = 0; n < 4; ++n)
              #pragma unroll
              for (int r = 0; r < 4; ++r)
                red[(mi * 16 + l4 * 4 + r) * 65 + n * 16 + l15] = gacc[p * 4 + mi][n][r];
        }
        __syncthreads();
        if (w == 1) {
          #pragma unroll
          for (int mi = 0; mi < 4; ++mi)
            #pragma unroll
            for (int n = 0; n < 4; ++n)
              #pragma unroll
              for (int r = 0; r < 4; ++r)
                red[(mi * 16 + l4 * 4 + r) * 65 + n * 16 + l15] += gacc[p * 4 + mi][n][r];
        }
        __syncthreads();
        if (w == 2) {
          #pragma unroll
          for (int mi = 0; mi < 4; ++mi)
            #pragma unroll
            for (int n = 0; n < 4; ++n)
              #pragma unroll
              for (int r = 0; r < 4; ++r)
                red[(mi * 16 + l4 * 4 + r) * 65 + n * 16 + l15] += gacc[p * 4 + mi][n][r];
        }
        __syncthreads();
        if (w == 3) {
          #pragma unroll
          for (int mi = 0; mi < 4; ++mi)
            #pragma unroll
            for (int n = 0; n < 4; ++n)
              #pragma unroll
              for (int r = 0; r < 4; ++r)
                red[(mi * 16 + l4 * 4 + r) * 65 + n * 16 + l15] += gacc[p * 4 + mi][n][r];
        }
        __syncthreads();
        #pragma unroll
        for (int q = 0; q < 16; ++q) {
          const int rl = q * 4 + w;
          og[(size_t)(row0 + p * 64 + rl) * 4096 + nb * 64 + (tid & 63)] =
              (_Float16)(red[rl * 65 + (tid & 63)] + bvf);
        }
      }
    }

    if (layer == 1) publish(a.flags, bid, (unsigned)(s + 2));
  }
}

__global__ __launch_bounds__(256) void readout(
    const float* __restrict__ hF, const float* __restrict__ Wro,
    const float* __restrict__ bro, float* __restrict__ out) {
  const int b = blockIdx.x;
  const int tid = threadIdx.x;
  float p = 0.f;
  for (int h = tid; h < H_; h += 256) p += hF[(size_t)b * H_ + h] * Wro[h];
  #pragma unroll
  for (int off = 32; off; off >>= 1) p += __shfl_down(p, off, 64);
  __shared__ float redr[4];
  if ((tid & 63) == 0) redr[tid >> 6] = p;
  __syncthreads();
  if (tid == 0) out[b] = redr[0] + redr[1] + redr[2] + redr[3] + bro[0];
}

extern "C" void kernel_launch(void* const* d_in, const int* in_sizes, int n_in,
                              void* d_out, int out_size, void* d_ws, size_t ws_size,
                              hipStream_t stream) {
  const float* init_hidden = (const float*)d_in[0];
  const float* ctx   = (const float*)d_in[1];
  const float* W_ih0 = (const float*)d_in[2];
  const float* W_hh0 = (const float*)d_in[3];
  const float* b_ih0 = (const float*)d_in[4];
  const float* b_hh0 = (const float*)d_in[5];
  const float* W_ih1 = (const float*)d_in[6];
  const float* W_hh1 = (const float*)d_in[7];
  const float* b_ih1 = (const float*)d_in[8];
  const float* b_hh1 = (const float*)d_in[9];
  const float* W_ro  = (const float*)d_in[10];
  const float* b_ro  = (const float*)d_in[11];

  char* ws = (char*)d_ws;
  const size_t MB = 1 << 20;
  _Float16* W0p    = (_Float16*)(ws);                      // 4 MiB
  _Float16* Wh0p   = (_Float16*)(ws + 4 * MB);             // 8 MiB
  _Float16* W1p    = (_Float16*)(ws + 12 * MB);            // 8 MiB
  _Float16* Wh1p   = (_Float16*)(ws + 20 * MB);            // 8 MiB
  float*    bs0    = (float*)(ws + 28 * MB);               // 16 KiB
  float*    bs1    = (float*)(ws + 28 * MB + 16384);       // 16 KiB
  float*    hF     = (float*)(ws + 28 * MB + 32768);       // 1 MiB
  _Float16* h1ring = (_Float16*)(ws + 29 * MB + 32768);    // 1 MiB (2 slots)
  _Float16* h2ring = (_Float16*)(ws + 30 * MB + 32768);    // 1 MiB
  _Float16* xg0    = (_Float16*)(ws + 31 * MB + 32768);    // 4 MiB (2 slots)
  _Float16* xg1    = (_Float16*)(ws + 35 * MB + 32768);    // 4 MiB
  unsigned* flags  = (unsigned*)(ws + 39 * MB + 32768);    // 1 KiB

  hipMemsetAsync(flags, 0, 4096, stream);
  prep_w<<<dim3(2, 4096), 256, 0, stream>>>(W0p, W_ih0, 512);
  prep_w<<<dim3(4, 4096), 256, 0, stream>>>(Wh0p, W_hh0, 1024);
  prep_w<<<dim3(4, 4096), 256, 0, stream>>>(W1p, W_ih1, 1024);
  prep_w<<<dim3(4, 4096), 256, 0, stream>>>(Wh1p, W_hh1, 1024);
  prep_bias<<<dim3(16), 256, 0, stream>>>(bs0, bs1, b_ih0, b_hh0, b_ih1, b_hh1);

  MegaArgs ma;
  ma.ctx = ctx; ma.W0p = W0p; ma.W1p = W1p; ma.Wh0p = Wh0p; ma.Wh1p = Wh1p;
  ma.bs0 = bs0; ma.bs1 = bs1; ma.h1ring = h1ring; ma.h2ring = h2ring;
  ma.xg0ring = xg0; ma.xg1ring = xg1; ma.hF = hF; ma.init = init_hidden;
  ma.flags = flags;
  mega<<<dim3(256), dim3(256), 0, stream>>>(ma);

  readout<<<dim3(256), 256, 0, stream>>>(hF, W_ro, b_ro, (float*)d_out);
}

// Round 8
// 8298.021 us; speedup vs baseline: 1.3427x; 1.3427x over previous
//
#include <hip/hip_runtime.h>
#include <hip/hip_bf16.h>

#define B_ 256
#define T_ 256
#define I_ 512
#define H_ 1024

typedef _Float16 half8 __attribute__((ext_vector_type(8)));
typedef _Float16 half4 __attribute__((ext_vector_type(4)));
typedef float floatx4 __attribute__((ext_vector_type(4)));

__device__ __forceinline__ float fsig(float x) { return 1.f / (1.f + __expf(-x)); }
__device__ __forceinline__ float ftanh(float x) { return 1.f - 2.f / (__expf(2.f * x) + 1.f); }

// agent-scope write-through f16 store (visible cross-XCD at L3 without L2 flush)
__device__ __forceinline__ void st_h16(_Float16* p, _Float16 v) {
  unsigned short u = __builtin_bit_cast(unsigned short, v);
  __hip_atomic_store((unsigned short*)p, u, __ATOMIC_RELAXED, __HIP_MEMORY_SCOPE_AGENT);
}

// agent-scope bypass load of 8 f16 (two 8B coherent loads; reads L3, skips stale L1/L2)
__device__ __forceinline__ half8 ld_bypass16(const _Float16* p) {
  unsigned long long lo = __hip_atomic_load((const unsigned long long*)p,
                                            __ATOMIC_RELAXED, __HIP_MEMORY_SCOPE_AGENT);
  unsigned long long hi = __hip_atomic_load((const unsigned long long*)(p + 4),
                                            __ATOMIC_RELAXED, __HIP_MEMORY_SCOPE_AGENT);
  half4 a = __builtin_bit_cast(half4, lo);
  half4 b = __builtin_bit_cast(half4, hi);
  half8 r;
  r[0] = a[0]; r[1] = a[1]; r[2] = a[2]; r[3] = a[3];
  r[4] = b[0]; r[5] = b[1]; r[6] = b[2]; r[7] = b[3];
  return r;
}

// Permuted gate-row order: n' -> orig row g*H + h, g=(n'&63)>>4, h=(n'>>6)*16+(n'&15).

__global__ __launch_bounds__(256) void prep_w(
    _Float16* __restrict__ dst, const float* __restrict__ src, int K) {
  const int np = blockIdx.y;
  const int k = blockIdx.x * 256 + threadIdx.x;
  const int cc = np & 63, g = cc >> 4, j = cc & 15;
  const int orig = g * H_ + (np >> 6) * 16 + j;
  dst[(size_t)np * K + k] = (_Float16)src[(size_t)orig * K + k];
}

__global__ __launch_bounds__(256) void prep_bias(
    float* __restrict__ bs0, float* __restrict__ bs1,
    const float* __restrict__ bih0, const float* __restrict__ bhh0,
    const float* __restrict__ bih1, const float* __restrict__ bhh1) {
  const int np = blockIdx.x * 256 + threadIdx.x;   // grid 16
  const int cc = np & 63, g = cc >> 4, j = cc & 15;
  const int orig = g * H_ + (np >> 6) * 16 + j;
  bs0[np] = bih0[orig] + bhh0[orig];
  bs1[np] = bih1[orig] + bhh1[orig];
}

struct MegaArgs {
  const float* ctx;
  const _Float16* W0p;  const _Float16* W1p;
  const _Float16* Wh0p; const _Float16* Wh1p;
  const float* bs0; const float* bs1;
  _Float16* h1ring; _Float16* h2ring;     // [2][B_*H_] cross-block via L3
  _Float16* xg0ring; _Float16* xg1ring;   // [2][B_*4096] block-local, L2-cached
  float* hF;
  const float* init;
  unsigned* flags;                        // [256] progress flags
};

__device__ __forceinline__ void publish(unsigned* flags, int bid, unsigned v) {
  __syncthreads();   // drains all this block's stores (vmcnt 0) before flag
  if (threadIdx.x == 0) {
    asm volatile("" ::: "memory");
    __hip_atomic_store(&flags[bid], v, __ATOMIC_RELAXED, __HIP_MEMORY_SCOPE_AGENT);
  }
}

// Wait until all 128 blocks of this strip (both layers) have published >= tgt.
// No acquire fence: all cross-block data reads go through ld_bypass16.
__device__ __forceinline__ void wait_strip(unsigned* flags, int strip, unsigned tgt) {
  if (threadIdx.x < 64) {
    unsigned* f0 = flags + strip * 64 + threadIdx.x;
    unsigned* f1 = flags + 128 + strip * 64 + threadIdx.x;
    for (;;) {
      const unsigned a = __hip_atomic_load(f0, __ATOMIC_RELAXED, __HIP_MEMORY_SCOPE_AGENT);
      const unsigned b = __hip_atomic_load(f1, __ATOMIC_RELAXED, __HIP_MEMORY_SCOPE_AGENT);
      if (__all(a >= tgt && b >= tgt)) break;
      __builtin_amdgcn_s_sleep(1);
    }
  }
  __syncthreads();
}

// GEMM tile: 128 rows x 64 cols (wave w = cols w*16..+16, all 128 rows), B in regs.
// AMODE 0: A fp32 cached (ctx). AMODE 1: A f16 agent-bypass (h1ring).
// Depth-3 register staging ring hides L3 latency across the per-chunk barriers.
template<int NC, int AMODE>
__device__ __forceinline__ void gemm_tile(
    const void* __restrict__ aptr, const half8* __restrict__ bf,
    _Float16* __restrict__ ab, floatx4 (&gacc)[8]) {
  const int tid = threadIdx.x;
  const int srow = tid >> 1;
  const int lane = tid & 63, l15 = lane & 15, l4 = lane >> 4;
  const float*    af32 = (const float*)aptr;
  const _Float16* af16 = (const _Float16*)aptr;
  half8 st[3][4];
  auto fetch = [&](int c, int slot) {
    #pragma unroll
    for (int p = 0; p < 4; ++p) {
      if (AMODE == 0) {
        float4 f0 = *(const float4*)(af32 + c * 64 + p * 8);
        float4 f1 = *(const float4*)(af32 + c * 64 + p * 8 + 4);
        half8 h;
        h[0] = (_Float16)f0.x; h[1] = (_Float16)f0.y;
        h[2] = (_Float16)f0.z; h[3] = (_Float16)f0.w;
        h[4] = (_Float16)f1.x; h[5] = (_Float16)f1.y;
        h[6] = (_Float16)f1.z; h[7] = (_Float16)f1.w;
        st[slot][p] = h;
      } else {
        st[slot][p] = ld_bypass16(af16 + c * 64 + p * 8);
      }
    }
  };
  fetch(0, 0); fetch(1, 1); fetch(2, 2);
  #pragma unroll
  for (int c = 0; c < NC; ++c) {
    const int slot = c % 3;
    __syncthreads();
    #pragma unroll
    for (int p = 0; p < 4; ++p) {
      const int g = (tid & 1) * 4 + p;
      *(half8*)(ab + srow * 64 + ((g ^ (srow & 7)) * 8)) = st[slot][p];
    }
    __syncthreads();
    if (c + 3 < NC) fetch(c + 3, slot);
    #pragma unroll
    for (int ks2 = 0; ks2 < 2; ++ks2) {
      #pragma unroll
      for (int m = 0; m < 8; ++m) {
        const int arow = m * 16 + l15;
        const int ga = ks2 * 4 + l4;
        half8 af = *(const half8*)(ab + arow * 64 + ((ga ^ (arow & 7)) * 8));
        gacc[m] = __builtin_amdgcn_mfma_f32_16x16x32_f16(af, bf[c * 2 + ks2], gacc[m], 0, 0, 0);
      }
    }
  }
}

// Persistent fused kernel: 256 blocks (1/CU). bid>>7=layer, (bid>>6)&1=strip, bid&63=colblock.
// Schedule: L0-rec t=s-1 (s:1..256); L0-gemm xg0[t=s] (s:0..255);
//           L1-gemm tau=s-2 (s:2..257); L1-rec t=s-3 (s:3..258). Rings depth 2.
__global__ __launch_bounds__(256, 1) void mega(MegaArgs a) {
  const int bid = blockIdx.x, tid = threadIdx.x;
  const int layer = bid >> 7, strip = (bid >> 6) & 1, nb = bid & 63;
  const int row0 = strip * 128;
  const int w = tid >> 6, lane = tid & 63, l15 = lane & 15, l4 = lane >> 4;

  __shared__ _Float16 whb[64 * 1024];   // 128 KB: resident W_hh slice (swizzled)
  __shared__ _Float16 ab[128 * 64];     // 16 KB: A-chunk (swizzled)

  // ---- init h rings (slot 1 = t=-1 state), write-through ----
  {
    const int idx = (bid * 256 + tid) * 4;
    const float4 v = *(const float4*)(a.init + idx);
    st_h16(a.h1ring + B_ * H_ + idx,     (_Float16)v.x);
    st_h16(a.h1ring + B_ * H_ + idx + 1, (_Float16)v.y);
    st_h16(a.h1ring + B_ * H_ + idx + 2, (_Float16)v.z);
    st_h16(a.h1ring + B_ * H_ + idx + 3, (_Float16)v.w);
    st_h16(a.h2ring + B_ * H_ + idx,     (_Float16)v.x);
    st_h16(a.h2ring + B_ * H_ + idx + 1, (_Float16)v.y);
    st_h16(a.h2ring + B_ * H_ + idx + 2, (_Float16)v.z);
    st_h16(a.h2ring + B_ * H_ + idx + 3, (_Float16)v.w);
  }

  // ---- stage resident W_hh slice -> LDS (swizzled granules) ----
  {
    const _Float16* Whp = (layer ? a.Wh1p : a.Wh0p) + (size_t)nb * 64 * 1024;
    const int row = tid & 63;
    const int gb = (tid >> 6) * 32;
    #pragma unroll
    for (int i = 0; i < 32; ++i) {
      const int g = gb + i;
      half8 v = *(const half8*)(Whp + (size_t)row * 1024 + g * 8);
      *(half8*)(whb + row * 1024 + ((g ^ (row & 7)) * 8)) = v;
    }
  }

  // ---- GEMM B-fragments -> registers ----
  const _Float16* Wg = layer ? a.W1p : a.W0p;
  const int gK = layer ? 1024 : 512;
  const int gcol = nb * 64 + w * 16 + l15;
  half8 bf[32];
  {
    const int nks = layer ? 32 : 16;
    #pragma unroll
    for (int ks = 0; ks < 32; ++ks)
      if (ks < nks)
        bf[ks] = *(const half8*)(Wg + (size_t)gcol * gK + ks * 32 + l4 * 8);
  }
  const float bv = (layer ? a.bs1 : a.bs0)[gcol];

  float cst[8] = {0.f, 0.f, 0.f, 0.f, 0.f, 0.f, 0.f, 0.f};
  const int hu = nb * 16 + l15;
  const int srow = tid >> 1;
  const int scol = (tid & 1) * 32;

  publish(a.flags, bid, 1u);

  for (int s = 0; s <= 258; ++s) {
    wait_strip(a.flags, strip, (unsigned)(s + 1));

    // ================= recurrent (h @ W_hh, K=1024, bypass-A, LDS-B) =================
    const bool recAct = layer ? (s >= 3 && s <= 258) : (s >= 1 && s <= 256);
    if (recAct) {
      const _Float16* Asrc = (layer ? a.h2ring : a.h1ring) + (size_t)(s & 1) * (B_ * H_);
      const _Float16* xg = (layer ? a.xg1ring : a.xg0ring) + (size_t)((s - 1) & 1) * (B_ * 4096);
      // staging geometry: srowR = tid>>3 (0..31), pieces p -> rows srowR + p*32
      const int srowR = tid >> 3;
      const int spc = (tid & 7) * 8;
      const _Float16* asrc = Asrc + (size_t)(row0 + srowR) * H_ + spc;
      floatx4 racc[2][4] = {};
      half8 st[3][4];
      auto fetchR = [&](int ki, int slot) {
        #pragma unroll
        for (int p = 0; p < 4; ++p)
          st[slot][p] = ld_bypass16(asrc + (size_t)(p * 32) * H_ + ki * 64);
      };
      fetchR(0, 0); fetchR(1, 1); fetchR(2, 2);
      #pragma unroll
      for (int c = 0; c < 16; ++c) {
        const int slot = c % 3;
        __syncthreads();
        #pragma unroll
        for (int p = 0; p < 4; ++p) {
          const int g = (tid & 7) + p * 0;  // placeholder avoided; real index below
        }
        #pragma unroll
        for (int p = 0; p < 4; ++p) {
          const int g = (tid & 7);
          // write piece: row srowR + p*32, granule (chunk-local col) = tid&7
          const int r = srowR + p * 32;
          *(half8*)(ab + r * 64 + (((tid & 7) ^ (r & 7)) * 8)) = st[slot][p];
        }
        __syncthreads();
        if (c + 3 < 16) fetchR(c + 3, slot);
        #pragma unroll
        for (int ks2 = 0; ks2 < 2; ++ks2) {
          half8 wbf[4];
          #pragma unroll
          for (int n = 0; n < 4; ++n) {
            const int wrow = n * 16 + l15;
            const int g = c * 8 + ks2 * 4 + l4;
            wbf[n] = *(const half8*)(whb + wrow * 1024 + ((g ^ (wrow & 7)) * 8));
          }
          #pragma unroll
          for (int m = 0; m < 2; ++m) {
            const int arow = w * 32 + m * 16 + l15;
            const int ga = ks2 * 4 + l4;
            half8 af = *(const half8*)(ab + arow * 64 + ((ga ^ (arow & 7)) * 8));
            #pragma unroll
            for (int n = 0; n < 4; ++n)
              racc[m][n] = __builtin_amdgcn_mfma_f32_16x16x32_f16(af, wbf[n], racc[m][n], 0, 0, 0);
          }
        }
      }
      // ---- register-local cell update (h writes agent write-through) ----
      const int t = layer ? (s - 3) : (s - 1);
      _Float16* hw = (layer ? a.h2ring : a.h1ring) + (size_t)((s - 1) & 1) * (B_ * H_);
      #pragma unroll
      for (int m = 0; m < 2; ++m) {
        #pragma unroll
        for (int r = 0; r < 4; ++r) {
          const int brow = row0 + w * 32 + m * 16 + l4 * 4 + r;
          const _Float16* xr = xg + (size_t)brow * 4096 + nb * 64;
          const float gi = racc[m][0][r] + (float)xr[l15];
          const float gf = racc[m][1][r] + (float)xr[16 + l15];
          const float gg = racc[m][2][r] + (float)xr[32 + l15];
          const float go = racc[m][3][r] + (float)xr[48 + l15];
          const float si = fsig(gi), sf = fsig(gf), so = fsig(go);
          const float tg = ftanh(gg);
          const float cn = sf * cst[m * 4 + r] + si * tg;
          const float hn = so * ftanh(cn);
          cst[m * 4 + r] = cn;
          st_h16(hw + (size_t)brow * H_ + hu, (_Float16)hn);
          if (layer == 1 && t == 255) a.hF[(size_t)brow * H_ + hu] = hn;
        }
      }
    }

    if (layer == 0) publish(a.flags, bid, (unsigned)(s + 2));  // h1[t=s-1] at L3

    // ================= input-GEMM slice (reg-B, staged A) =================
    const bool gAct = layer ? (s >= 2 && s <= 257) : (s <= 255);
    if (gAct) {
      _Float16* og = (layer ? a.xg1ring : a.xg0ring) + (size_t)(s & 1) * (B_ * 4096);
      floatx4 gacc[8] = {};
      if (layer) {
        const _Float16* abase = a.h1ring + (size_t)(s & 1) * (B_ * H_)
                              + (size_t)(row0 + srow) * H_ + scol;
        gemm_tile<16, 1>(abase, bf, ab, gacc);
      } else {
        const float* abase = a.ctx + ((size_t)(row0 + srow) * T_ + s) * I_ + scol;
        gemm_tile<8, 0>(abase, bf, ab, gacc);
      }
      #pragma unroll
      for (int m = 0; m < 8; ++m) {
        #pragma unroll
        for (int r = 0; r < 4; ++r)
          og[(size_t)(row0 + m * 16 + l4 * 4 + r) * 4096 + gcol] = (_Float16)(gacc[m][r] + bv);
      }
    }

    if (layer == 1) publish(a.flags, bid, (unsigned)(s + 2));
  }
}

__global__ __launch_bounds__(256) void readout(
    const float* __restrict__ hF, const float* __restrict__ Wro,
    const float* __restrict__ bro, float* __restrict__ out) {
  const int b = blockIdx.x;
  const int tid = threadIdx.x;
  float p = 0.f;
  for (int h = tid; h < H_; h += 256) p += hF[(size_t)b * H_ + h] * Wro[h];
  #pragma unroll
  for (int off = 32; off; off >>= 1) p += __shfl_down(p, off, 64);
  __shared__ float redr[4];
  if ((tid & 63) == 0) redr[tid >> 6] = p;
  __syncthreads();
  if (tid == 0) out[b] = redr[0] + redr[1] + redr[2] + redr[3] + bro[0];
}

extern "C" void kernel_launch(void* const* d_in, const int* in_sizes, int n_in,
                              void* d_out, int out_size, void* d_ws, size_t ws_size,
                              hipStream_t stream) {
  const float* init_hidden = (const float*)d_in[0];
  const float* ctx   = (const float*)d_in[1];
  const float* W_ih0 = (const float*)d_in[2];
  const float* W_hh0 = (const float*)d_in[3];
  const float* b_ih0 = (const float*)d_in[4];
  const float* b_hh0 = (const float*)d_in[5];
  const float* W_ih1 = (const float*)d_in[6];
  const float* W_hh1 = (const float*)d_in[7];
  const float* b_ih1 = (const float*)d_in[8];
  const float* b_hh1 = (const float*)d_in[9];
  const float* W_ro  = (const float*)d_in[10];
  const float* b_ro  = (const float*)d_in[11];

  char* ws = (char*)d_ws;
  const size_t MB = 1 << 20;
  _Float16* W0p    = (_Float16*)(ws);                      // 4 MiB
  _Float16* Wh0p   = (_Float16*)(ws + 4 * MB);             // 8 MiB
  _Float16* W1p    = (_Float16*)(ws + 12 * MB);            // 8 MiB
  _Float16* Wh1p   = (_Float16*)(ws + 20 * MB);            // 8 MiB
  float*    bs0    = (float*)(ws + 28 * MB);               // 16 KiB
  float*    bs1    = (float*)(ws + 28 * MB + 16384);       // 16 KiB
  float*    hF     = (float*)(ws + 28 * MB + 32768);       // 1 MiB
  _Float16* h1ring = (_Float16*)(ws + 29 * MB + 32768);    // 1 MiB (2 slots)
  _Float16* h2ring = (_Float16*)(ws + 30 * MB + 32768);    // 1 MiB
  _Float16* xg0    = (_Float16*)(ws + 31 * MB + 32768);    // 4 MiB (2 slots)
  _Float16* xg1    = (_Float16*)(ws + 35 * MB + 32768);    // 4 MiB
  unsigned* flags  = (unsigned*)(ws + 39 * MB + 32768);    // 1 KiB

  hipMemsetAsync(flags, 0, 4096, stream);
  prep_w<<<dim3(2, 4096), 256, 0, stream>>>(W0p, W_ih0, 512);
  prep_w<<<dim3(4, 4096), 256, 0, stream>>>(Wh0p, W_hh0, 1024);
  prep_w<<<dim3(4, 4096), 256, 0, stream>>>(W1p, W_ih1, 1024);
  prep_w<<<dim3(4, 4096), 256, 0, stream>>>(Wh1p, W_hh1, 1024);
  prep_bias<<<dim3(16), 256, 0, stream>>>(bs0, bs1, b_ih0, b_hh0, b_ih1, b_hh1);

  MegaArgs ma;
  ma.ctx = ctx; ma.W0p = W0p; ma.W1p = W1p; ma.Wh0p = Wh0p; ma.Wh1p = Wh1p;
  ma.bs0 = bs0; ma.bs1 = bs1; ma.h1ring = h1ring; ma.h2ring = h2ring;
  ma.xg0ring = xg0; ma.xg1ring = xg1; ma.hF = hF; ma.init = init_hidden;
  ma.flags = flags;
  mega<<<dim3(256), dim3(256), 0, stream>>>(ma);

  readout<<<dim3(256), 256, 0, stream>>>(hF, W_ro, b_ro, (float*)d_out);
}